// Round 1
// baseline (82.604 us; speedup 1.0000x reference)
//
#include <hip/hip_runtime.h>
#include <cfloat>

#define BB    128
#define CC    4
#define NBOXN 131072
#define SPLIT 16   // chunk-blocks per row

// Insert v into descending top-3 triple (a >= b >= c).
__device__ __forceinline__ void ins3(float v, float& a, float& b, float& c) {
    if (v > c) {
        if (v > b) {
            c = b;
            if (v > a) { b = a; a = v; }
            else       { b = v; }
        } else {
            c = v;
        }
    }
}

// Kernel 1: per (row, chunk) block, compute top-3 of class_preds[row, chunk],
// excluding the positive anchor index. Writes 3 floats per block to d_ws.
__global__ __launch_bounds__(256) void k_top3_partial(
        const float* __restrict__ cp,
        const int*   __restrict__ box_idxs,
        float*       __restrict__ part) {
    const int row   = blockIdx.x / SPLIT;
    const int chunk = blockIdx.x % SPLIT;
    const int bidx  = box_idxs[row];
    const int per_chunk = NBOXN / SPLIT;          // 8192 elements
    const int base  = chunk * per_chunk;
    const float4* src = reinterpret_cast<const float4*>(
        cp + (size_t)row * NBOXN + base);
    const int n4 = per_chunk / 4;                 // 2048 float4s

    float a = -FLT_MAX, b = -FLT_MAX, c = -FLT_MAX;
    for (int j = threadIdx.x; j < n4; j += 256) {
        float4 v = src[j];
        int g = base + j * 4;
        ins3((g     == bidx) ? -FLT_MAX : v.x, a, b, c);
        ins3((g + 1 == bidx) ? -FLT_MAX : v.y, a, b, c);
        ins3((g + 2 == bidx) ? -FLT_MAX : v.z, a, b, c);
        ins3((g + 3 == bidx) ? -FLT_MAX : v.w, a, b, c);
    }

    // wave64 shfl_down tree; only lane 0's cone is used (no dup pollution there)
    for (int off = 32; off >= 1; off >>= 1) {
        float a2 = __shfl_down(a, off);
        float b2 = __shfl_down(b, off);
        float c2 = __shfl_down(c, off);
        ins3(a2, a, b, c);
        ins3(b2, a, b, c);
        ins3(c2, a, b, c);
    }

    __shared__ float sm[4][3];
    const int lane = threadIdx.x & 63;
    const int wave = threadIdx.x >> 6;
    if (lane == 0) { sm[wave][0] = a; sm[wave][1] = b; sm[wave][2] = c; }
    __syncthreads();
    if (threadIdx.x == 0) {
        for (int w = 1; w < 4; ++w) {
            ins3(sm[w][0], a, b, c);
            ins3(sm[w][1], a, b, c);
            ins3(sm[w][2], a, b, c);
        }
        float* dst = part + (size_t)blockIdx.x * 3;
        dst[0] = a; dst[1] = b; dst[2] = c;
    }
}

// stable BCE-with-logits, matching reference: max(x,0) - x*t + log1p(exp(-|x|))
__device__ __forceinline__ float bce(float x, float t) {
    return fmaxf(x, 0.0f) - x * t + log1pf(expf(-fabsf(x)));
}

// Kernel 2: one block, 128 threads (one per row). Merge partial top-3s,
// compute class BCE + reg smooth-L1, reduce to scalar.
__global__ __launch_bounds__(128) void k_finalize(
        const float* __restrict__ part,
        const float* __restrict__ cp,
        const float* __restrict__ rp,
        const int*   __restrict__ box_idxs,
        const float* __restrict__ rt,
        float*       __restrict__ out) {
    const int row = threadIdx.x;   // 0..127
    float loss;
    {
        float a = -FLT_MAX, b = -FLT_MAX, c = -FLT_MAX;
        const float* p = part + (size_t)row * SPLIT * 3;
        #pragma unroll
        for (int k = 0; k < SPLIT * 3; ++k) ins3(p[k], a, b, c);

        const int bidx = box_idxs[row];
        const float pos = cp[(size_t)row * NBOXN + bidx];
        // class loss contributions (positive target=1, three negatives target=0)
        loss = bce(pos, 1.0f) + bce(a, 0.0f) + bce(b, 0.0f) + bce(c, 0.0f);
        // smooth-L1 on the gathered regression preds
        #pragma unroll
        for (int ci = 0; ci < CC; ++ci) {
            float pv = rp[((size_t)row * CC + ci) * NBOXN + bidx];
            float d  = fabsf(pv - rt[row * CC + ci]);
            loss += (d < 1.0f) ? 0.5f * d * d : (d - 0.5f);
        }
    }
    // sum over 128 threads (2 waves)
    for (int off = 32; off >= 1; off >>= 1) loss += __shfl_down(loss, off);
    __shared__ float sm[2];
    const int lane = threadIdx.x & 63;
    const int wave = threadIdx.x >> 6;
    if (lane == 0) sm[wave] = loss;
    __syncthreads();
    if (threadIdx.x == 0) {
        // class_loss = class_sum/512, reg_loss = reg_sum/512 -> total = sum/512
        out[0] = (sm[0] + sm[1]) / (float)(BB * CC);
    }
}

extern "C" void kernel_launch(void* const* d_in, const int* in_sizes, int n_in,
                              void* d_out, int out_size, void* d_ws, size_t ws_size,
                              hipStream_t stream) {
    const float* class_preds = (const float*)d_in[0];
    const float* reg_preds   = (const float*)d_in[1];
    const int*   box_idxs    = (const int*)d_in[2];
    const float* reg_targs   = (const float*)d_in[3];
    float* out  = (float*)d_out;
    float* part = (float*)d_ws;   // BB*SPLIT*3 floats = 24 KB

    k_top3_partial<<<BB * SPLIT, 256, 0, stream>>>(class_preds, box_idxs, part);
    k_finalize<<<1, 128, 0, stream>>>(part, class_preds, reg_preds,
                                      box_idxs, reg_targs, out);
}

// Round 2
// 38.519 us; speedup vs baseline: 2.1445x; 2.1445x over previous
//
#include <hip/hip_runtime.h>
#include <cfloat>

#define BB    128
#define CC    4
#define NBOXN 131072
#define SPLIT 16                 // chunk-blocks per row
#define F4_PER_CHUNK 2048        // 8192 elems / 4
#define STRIPES_PER_ROW (SPLIT * 256)   // 4096
#define F4_PER_STRIPE 8          // 2048 / 256 threads

// ---------------- Kernel 1: per-thread stripe max (anchor excluded) --------
// Stripe id s = chunk*256 + tid; its elements are float4 indices
// j = chunk*2048 + tid + 256*k (k=0..7) within the row.
__global__ __launch_bounds__(256) void k_stripe_max(
        const float* __restrict__ cp,
        const int*   __restrict__ box_idxs,
        float*       __restrict__ smax) {
    const int row   = blockIdx.x >> 4;
    const int chunk = blockIdx.x & 15;
    const int bidx  = box_idxs[row];
    const float4* src = reinterpret_cast<const float4*>(
        cp + (size_t)row * NBOXN) + chunk * F4_PER_CHUNK;
    const int gbase = chunk * (F4_PER_CHUNK * 4);

    float mx = -FLT_MAX, my = -FLT_MAX, mz = -FLT_MAX, mw = -FLT_MAX;
    #pragma unroll
    for (int k = 0; k < F4_PER_STRIPE; ++k) {
        const int j = threadIdx.x + (k << 8);
        float4 v = src[j];
        const int g = gbase + (j << 2);
        if ((unsigned)(bidx - g) < 4u) {        // rare: anchor in this float4
            if      (bidx == g)     v.x = -FLT_MAX;
            else if (bidx == g + 1) v.y = -FLT_MAX;
            else if (bidx == g + 2) v.z = -FLT_MAX;
            else                    v.w = -FLT_MAX;
        }
        mx = fmaxf(mx, v.x); my = fmaxf(my, v.y);
        mz = fmaxf(mz, v.z); mw = fmaxf(mw, v.w);
    }
    const float m = fmaxf(fmaxf(mx, my), fmaxf(mz, mw));
    smax[((size_t)row * SPLIT + chunk) * 256 + threadIdx.x] = m;
}

// ---------------- small helpers ----------------
__device__ __forceinline__ void ins3(float v, float& a, float& b, float& c) {
    // branchless sorted-insert into descending (a>=b>=c)
    float m1 = fminf(a, v); a = fmaxf(a, v);
    float m2 = fminf(b, m1); b = fmaxf(b, m1);
    c = fmaxf(c, m2);
}

__device__ __forceinline__ void ins3i(float v, int i,
                                      float& a, float& b, float& c,
                                      int& ia, int& ib, int& ic) {
    if (v > c) {
        if (v > b) {
            c = b; ic = ib;
            if (v > a) { b = a; ib = ia; a = v; ia = i; }
            else       { b = v; ib = i; }
        } else { c = v; ic = i; }
    }
}

__device__ __forceinline__ float bce(float x, float t) {
    return fmaxf(x, 0.0f) - x * t + log1pf(expf(-fabsf(x)));
}

// ---------------- Kernel 2: per-row top-3 + loss ----------------
__global__ __launch_bounds__(256) void k_row(
        const float* __restrict__ cp,
        const float* __restrict__ rp,
        const int*   __restrict__ box_idxs,
        const float* __restrict__ rt,
        const float* __restrict__ smax,
        float*       __restrict__ rowloss) {
    const int row = blockIdx.x;
    const int tid = threadIdx.x;
    const int bidx = box_idxs[row];
    const float* sm = smax + (size_t)row * STRIPES_PER_ROW;

    // ---- phase 1: top-3 (value, stripe) among 4096 stripe maxima ----
    float a = -FLT_MAX, b = -FLT_MAX, c = -FLT_MAX;
    int   ia = 0, ib = 0, ic = 0;
    #pragma unroll
    for (int k = 0; k < STRIPES_PER_ROW / 256; ++k) {
        const int s = tid + (k << 8);
        ins3i(sm[s], s, a, b, c, ia, ib, ic);
    }
    for (int off = 32; off >= 1; off >>= 1) {
        float a2 = __shfl_down(a, off), b2 = __shfl_down(b, off), c2 = __shfl_down(c, off);
        int  ia2 = __shfl_down(ia, off), ib2 = __shfl_down(ib, off), ic2 = __shfl_down(ic, off);
        ins3i(a2, ia2, a, b, c, ia, ib, ic);
        ins3i(b2, ib2, a, b, c, ia, ib, ic);
        ins3i(c2, ic2, a, b, c, ia, ib, ic);
    }
    __shared__ float sv[4][3];
    __shared__ int   si[4][3];
    __shared__ int   top_stripe[3];
    const int lane = tid & 63, wave = tid >> 6;
    if (lane == 0) {
        sv[wave][0] = a; sv[wave][1] = b; sv[wave][2] = c;
        si[wave][0] = ia; si[wave][1] = ib; si[wave][2] = ic;
    }
    __syncthreads();
    if (tid == 0) {
        for (int w = 1; w < 4; ++w) {
            ins3i(sv[w][0], si[w][0], a, b, c, ia, ib, ic);
            ins3i(sv[w][1], si[w][1], a, b, c, ia, ib, ic);
            ins3i(sv[w][2], si[w][2], a, b, c, ia, ib, ic);
        }
        top_stripe[0] = ia; top_stripe[1] = ib; top_stripe[2] = ic;
    }
    __syncthreads();

    // ---- phase 2: exact top-3 by rescanning the 3 candidate stripes ----
    // 3 stripes x 8 float4 = 24 float4 (96 elements)
    float ra = -FLT_MAX, rb = -FLT_MAX, rc = -FLT_MAX;
    if (tid < 3 * F4_PER_STRIPE) {
        const int st = tid >> 3, k = tid & 7;
        const int s = top_stripe[st];
        const int chunk = s >> 8, lt = s & 255;
        const int j = chunk * F4_PER_CHUNK + lt + (k << 8);
        float4 v = reinterpret_cast<const float4*>(cp + (size_t)row * NBOXN)[j];
        const int g = j << 2;
        if ((unsigned)(bidx - g) < 4u) {
            if      (bidx == g)     v.x = -FLT_MAX;
            else if (bidx == g + 1) v.y = -FLT_MAX;
            else if (bidx == g + 2) v.z = -FLT_MAX;
            else                    v.w = -FLT_MAX;
        }
        ins3(v.x, ra, rb, rc); ins3(v.y, ra, rb, rc);
        ins3(v.z, ra, rb, rc); ins3(v.w, ra, rb, rc);
    }
    for (int off = 32; off >= 1; off >>= 1) {
        float a2 = __shfl_down(ra, off), b2 = __shfl_down(rb, off), c2 = __shfl_down(rc, off);
        ins3(a2, ra, rb, rc); ins3(b2, ra, rb, rc); ins3(c2, ra, rb, rc);
    }
    if (lane == 0) { sv[wave][0] = ra; sv[wave][1] = rb; sv[wave][2] = rc; }
    __syncthreads();

    // ---- phase 3: loss for this row ----
    if (tid == 0) {
        for (int w = 1; w < 4; ++w) {
            ins3(sv[w][0], ra, rb, rc);
            ins3(sv[w][1], ra, rb, rc);
            ins3(sv[w][2], ra, rb, rc);
        }
        const float pos = cp[(size_t)row * NBOXN + bidx];
        float loss = bce(pos, 1.0f) + bce(ra, 0.0f) + bce(rb, 0.0f) + bce(rc, 0.0f);
        #pragma unroll
        for (int ci = 0; ci < CC; ++ci) {
            const float pv = rp[((size_t)row * CC + ci) * NBOXN + bidx];
            const float d  = fabsf(pv - rt[row * CC + ci]);
            loss += (d < 1.0f) ? 0.5f * d * d : (d - 0.5f);
        }
        rowloss[row] = loss;
    }
}

// ---------------- Kernel 3: scalar reduce ----------------
__global__ __launch_bounds__(128) void k_reduce(
        const float* __restrict__ rowloss, float* __restrict__ out) {
    float v = rowloss[threadIdx.x];
    for (int off = 32; off >= 1; off >>= 1) v += __shfl_down(v, off);
    __shared__ float sm[2];
    const int lane = threadIdx.x & 63, wave = threadIdx.x >> 6;
    if (lane == 0) sm[wave] = v;
    __syncthreads();
    if (threadIdx.x == 0) out[0] = (sm[0] + sm[1]) / (float)(BB * CC);
}

extern "C" void kernel_launch(void* const* d_in, const int* in_sizes, int n_in,
                              void* d_out, int out_size, void* d_ws, size_t ws_size,
                              hipStream_t stream) {
    const float* class_preds = (const float*)d_in[0];
    const float* reg_preds   = (const float*)d_in[1];
    const int*   box_idxs    = (const int*)d_in[2];
    const float* reg_targs   = (const float*)d_in[3];
    float* out = (float*)d_out;

    float* smax    = (float*)d_ws;                         // 128*4096 floats = 2 MiB
    float* rowloss = smax + (size_t)BB * STRIPES_PER_ROW;  // 128 floats

    k_stripe_max<<<BB * SPLIT, 256, 0, stream>>>(class_preds, box_idxs, smax);
    k_row<<<BB, 256, 0, stream>>>(class_preds, reg_preds, box_idxs,
                                  reg_targs, smax, rowloss);
    k_reduce<<<1, 128, 0, stream>>>(rowloss, out);
}